// Round 1
// 311.239 us; speedup vs baseline: 1.0134x; 1.0134x over previous
//
#include <hip/hip_runtime.h>

// Head_13: fused single-head causal attention, B=1024 T=128 C=384 HS=64, fp32 I/O.
// One block (4 waves) per batch. bf16 MFMA 32x32x16.
// Phase 1 (QKV proj): x staged to LDS via coalesced global_load_lds (16B, XOR-swizzled
// source, linear LDS dest), double-buffered in the dead Q+K region; W pre-packed to
// fragment-major bf16 (L2-resident). Frees the old 64-VGPR register x-buffer so
// __launch_bounds__(256,3) fits 3 blocks/CU (was register-capped at 2).
// Phase 2: LDS q/k/v, causal flash in-block, rowsum via shfl_xor butterfly.

typedef __attribute__((ext_vector_type(8)))  short  short8;   // 8 bf16 = 4 VGPR
typedef __attribute__((ext_vector_type(16))) float  floatx16; // MFMA 32x32 acc
typedef __attribute__((ext_vector_type(4)))  float  float4v;

#define T_DIM   128
#define C_DIM   384
#define HS      64
#define NCHUNK  12            // 384/32
#define SLAB    1536          // shorts per (c,ks,half) slab = 192 n * 8 k

#define QK_PITCH 68           // 64+4 bf16 -> 136 B row (8B-aligned, 2-way banks = free)
#define V_PITCH  132          // 128+4 bf16 -> 264 B
#define P_PITCH  132
#define Q_OFF 0
#define K_OFF 17408           // 128*136
#define V_OFF 34816
#define LDS_BYTES 51712       // V_OFF + 64*264
#define P_OFF 0               // P [128][132]*2 = 33792 overlays q + head of k (dead in 2b)
#define XS_OFF 0              // x staging: 2 x 16384 B overlays Q+K (dead until epilogue)
#define XS_BUF 16384          // one chunk: 128 rows x 128 B (32 fp32), XOR-swizzled

#define MFMA(a,b,c) __builtin_amdgcn_mfma_f32_32x32x16_bf16((a),(b),(c),0,0,0)

__device__ inline unsigned short f2bf(float f){ // fp32 -> bf16 RTNE
    unsigned u = __builtin_bit_cast(unsigned, f);
    u += 0x7FFFu + ((u >> 16) & 1u);
    return (unsigned short)(u >> 16);
}

__device__ inline short8 ld_b64x2(const char* p){ // 16B fragment via two 8B LDS reads
    union { unsigned long long u[2]; short8 s; } r;
    r.u[0] = *(const unsigned long long*)(p);
    r.u[1] = *(const unsigned long long*)(p + 8);
    return r.s;
}

// W[q|k|v] fp32 [384][64] -> wt bf16 fragment-major: [c][ks][half][n=192][j=8]
// short index = ((c*2+ks)*2+half)*1536 + n*8 + j ; k_global = c*32+ks*16+half*8+j
__global__ void prep_wt(const float* __restrict__ Wq, const float* __restrict__ Wk,
                        const float* __restrict__ Wv, unsigned short* __restrict__ wt){
    int idx = blockIdx.x * 256 + threadIdx.x;
    if (idx >= 48 * SLAB) return;
    int slab = idx / SLAB;
    int rem  = idx - slab * SLAB;
    int n = rem >> 3, j = rem & 7;
    int half = slab & 1, ks = (slab >> 1) & 1, c = slab >> 2;
    int kg = c*32 + ks*16 + half*8 + j;
    const float* W = (n < 64) ? Wq : (n < 128) ? Wk : Wv;
    wt[idx] = f2bf(W[kg * HS + (n & 63)]);
}

__launch_bounds__(256, 3)
__global__ void attn_kernel(const float* __restrict__ x,
                            const unsigned short* __restrict__ wtg,
                            float* __restrict__ out){
    __shared__ __align__(16) char smem[LDS_BYTES];
    const int tid  = threadIdx.x;
    const int lane = tid & 63;
    const int wave = tid >> 6;
    const int l31  = lane & 31;
    const int half = lane >> 5;
    const int koff = half * 8;            // MFMA k-split: lanes 32-63 hold k+8..k+15
    const int b    = blockIdx.x;
    const float* xb = x + (size_t)b * (T_DIM * C_DIM);

    // ---------------- phase 1: [q|k|v] = x[b] @ Wt ------------------------------
    // x chunk (128 rows x 32 fp32) staged to LDS, coalesced, double-buffered.
    // LDS layout is LINEAR (global_load_lds writes base + lane*16); the XOR swizzle
    // lives in the per-lane GLOBAL source address: LDS[r][cb] = x[r][cb ^ ((r&7)<<4)].
    // Readers apply the same XOR -> ds_read_b128 fragment gather is 4-way (not 32-way).
    const int mpair = wave & 1;           // rows 64*mpair .. +63 (2 M-blocks)
    const int ntri  = wave >> 1;          // wt cols 96*ntri .. +95 (3 N-blocks)
    const short8* wf = (const short8*)wtg;
    const int nbase = 96 * ntri + l31;

    // per-lane staging source: row group (lane>>3), 16B block (lane&7)^(lane>>3)
    const char* xsrc = (const char*)xb
                     + (lane >> 3) * (C_DIM * 4)
                     + ((((lane & 7) ^ (lane >> 3))) << 4);

    auto stage = [&](int c, int sb){
        #pragma unroll
        for (int i = 0; i < 4; ++i){
            const char* g = xsrc + (i*4 + wave) * (8 * C_DIM * 4) + c * 128;
            char*       l = smem + XS_OFF + sb * XS_BUF + (i*4 + wave) * 1024;
            __builtin_amdgcn_global_load_lds(
                (const __attribute__((address_space(1))) unsigned*)g,
                (__attribute__((address_space(3))) unsigned*)l,
                16, 0, 0);
        }
    };

    floatx16 acc[6] = {};                 // [nbl*2 + mbl]
    stage(0, 0);

    #pragma unroll
    for (int c = 0; c < NCHUNK; ++c){
        // barrier also drains vmcnt(0): stage(c) landed; buf[(c+1)&1] free to restage
        __syncthreads();

        // B fragments for this chunk (global wt, L2-resident) — issued before stage
        short8 bfr[2][3];
        #pragma unroll
        for (int ks = 0; ks < 2; ++ks)
            #pragma unroll
            for (int nbl = 0; nbl < 3; ++nbl)
                bfr[ks][nbl] = wf[((c*2 + ks)*2 + half)*192 + nbase + 32*nbl];

        if (c + 1 < NCHUNK) stage(c + 1, (c + 1) & 1);  // flies under compute below

        // A fragments: swizzled LDS read + fp32->bf16 convert
        const char* sbuf = smem + XS_OFF + (c & 1) * XS_BUF;
        short8 afr[2][2];
        #pragma unroll
        for (int mbl = 0; mbl < 2; ++mbl){
            const int R  = 64*mpair + 32*mbl + l31;
            const char* rp = sbuf + R * 128;
            const int sw = (R & 7) << 4;
            #pragma unroll
            for (int ks = 0; ks < 2; ++ks){
                const int cb = ks*64 + half*32;        // byte col of 8-fp32 fragment
                float4v lo = *(const float4v*)(rp + ((cb     ) ^ sw));
                float4v hi = *(const float4v*)(rp + ((cb + 16) ^ sw));
                short8 a;
                a[0]=(short)f2bf(lo[0]); a[1]=(short)f2bf(lo[1]);
                a[2]=(short)f2bf(lo[2]); a[3]=(short)f2bf(lo[3]);
                a[4]=(short)f2bf(hi[0]); a[5]=(short)f2bf(hi[1]);
                a[6]=(short)f2bf(hi[2]); a[7]=(short)f2bf(hi[3]);
                afr[ks][mbl] = a;
            }
        }
        #pragma unroll
        for (int ks = 0; ks < 2; ++ks)
            #pragma unroll
            for (int nbl = 0; nbl < 3; ++nbl){
                acc[nbl*2+0] = MFMA(afr[ks][0], bfr[ks][nbl], acc[nbl*2+0]);
                acc[nbl*2+1] = MFMA(afr[ks][1], bfr[ks][nbl], acc[nbl*2+1]);
            }
    }
    __syncthreads();   // all staging reads done before q/k epilogue overwrites region

    // write q,k (row-major, softmax scale*log2e folded into q) and v (h-major) to LDS
    const float QSCALE = 0.125f * 1.44269504088896f;
    #pragma unroll
    for (int nbl = 0; nbl < 3; ++nbl)
        #pragma unroll
        for (int mbl = 0; mbl < 2; ++mbl){
            floatx16 A = acc[nbl*2+mbl];
            int nb = 3*ntri + nbl;        // 0..5: q q k k v v
            int mb = 2*mpair + mbl;
            if (nb < 4){
                int base  = (nb < 2) ? Q_OFF : K_OFF;
                int col   = 32 * (nb & 1) + l31;
                float sc  = (nb < 2) ? QSCALE : 1.0f;
                char* bp  = smem + base + col * 2;
                #pragma unroll
                for (int r = 0; r < 16; ++r){
                    int t = 32*mb + (r&3) + 8*(r>>2) + 4*half;   // verified C/D row map
                    *(unsigned short*)(bp + t * (QK_PITCH*2)) = f2bf(A[r] * sc);
                }
            } else {
                int h = 32*(nb-4) + l31;
                char* bp = smem + V_OFF + h * (V_PITCH*2);
                #pragma unroll
                for (int g = 0; g < 4; ++g){
                    int t0 = 32*mb + 8*g + 4*half;   // regs 4g..4g+3 = 4 consecutive rows
                    union { unsigned short s[4]; unsigned long long u; } pk;
                    pk.s[0]=f2bf(A[4*g+0]); pk.s[1]=f2bf(A[4*g+1]);
                    pk.s[2]=f2bf(A[4*g+2]); pk.s[3]=f2bf(A[4*g+3]);
                    *(unsigned long long*)(bp + t0*2) = pk.u;
                }
            }
        }
    __syncthreads();

    // ---------------- phase 2a: S = q k^T (causal), P = exp2(S) ----------------
    // wave w owns rows [32w, 32w+32); tiles st > w fully masked -> skipped.
    floatx16 accS[4] = {};
    #pragma unroll
    for (int ks = 0; ks < 4; ++ks){
        short8 aq = ld_b64x2(smem + Q_OFF + (32*wave + l31)*(QK_PITCH*2) + (ks*16 + koff)*2);
        #pragma unroll
        for (int st = 0; st < 4; ++st)
            if (st <= wave){
                short8 bk = ld_b64x2(smem + K_OFF + (32*st + l31)*(QK_PITCH*2) + (ks*16 + koff)*2);
                accS[st] = MFMA(aq, bk, accS[st]);
            }
    }
    // |logit| <~ 8 -> exp2 safe in fp32 without max-subtraction
    #pragma unroll
    for (int st = 0; st < 4; ++st)
        if (st <= wave){
            #pragma unroll
            for (int r = 0; r < 16; ++r){
                int trow = (r&3) + 8*(r>>2) + 4*half;
                float e = exp2f(accS[st][r]);
                if (st == wave && l31 > trow) e = 0.0f;   // causal mask, diagonal tile
                accS[st][r] = e;
            }
        }

    // rowsum -> 1/l per (reg, half) via butterfly within each 32-lane half.
    // accS[st] for st > wave is still all-zero, so sum all 4 unconditionally.
    float linv[16];
    #pragma unroll
    for (int r = 0; r < 16; ++r){
        float l = accS[0][r] + accS[1][r] + accS[2][r] + accS[3][r];
        #pragma unroll
        for (int m = 1; m <= 16; m <<= 1)
            l += __shfl_xor(l, m);
        linv[r] = 1.0f / l;
    }
    __syncthreads();     // all waves done reading q,k (P overlays them)

    // ---------------- phase 2b: P -> LDS (A-layout), O = P v -------------------
    #pragma unroll
    for (int st = 0; st < 4; ++st)
        if (st <= wave){
            char* bp = smem + P_OFF + (32*st + l31) * 2;
            #pragma unroll
            for (int r = 0; r < 16; ++r){
                int t = 32*wave + (r&3) + 8*(r>>2) + 4*half;
                *(unsigned short*)(bp + t * (P_PITCH*2)) = f2bf(accS[st][r]);
            }
        }
    __syncthreads();

    floatx16 accO0 = {}, accO1 = {};
    const int nks = 2 * (wave + 1);       // P == 0 / unwritten beyond diagonal block
    #pragma unroll
    for (int ks = 0; ks < 8; ++ks)
        if (ks < nks){
            short8 ap  = ld_b64x2(smem + P_OFF + (32*wave + l31)*(P_PITCH*2) + (ks*16 + koff)*2);
            short8 bv0 = ld_b64x2(smem + V_OFF + l31        *(V_PITCH*2) + (ks*16 + koff)*2);
            short8 bv1 = ld_b64x2(smem + V_OFF + (l31 + 32) *(V_PITCH*2) + (ks*16 + koff)*2);
            accO0 = MFMA(ap, bv0, accO0);
            accO1 = MFMA(ap, bv1, accO1);
        }

    // normalize with register-resident 1/l and store fp32 (coalesced over l31)
    float* ob = out + (size_t)b * (T_DIM * HS);
    #pragma unroll
    for (int r = 0; r < 16; ++r){
        int t = 32*wave + (r&3) + 8*(r>>2) + 4*half;
        ob[t*HS + l31]      = accO0[r] * linv[r];
        ob[t*HS + l31 + 32] = accO1[r] * linv[r];
    }
}

extern "C" void kernel_launch(void* const* d_in, const int* in_sizes, int n_in,
                              void* d_out, int out_size, void* d_ws, size_t ws_size,
                              hipStream_t stream){
    const float* x  = (const float*)d_in[0];
    const float* Wq = (const float*)d_in[1];
    const float* Wk = (const float*)d_in[2];
    const float* Wv = (const float*)d_in[3];
    unsigned short* wt = (unsigned short*)d_ws;   // 48*1536*2 = 147456 B used

    prep_wt<<<288, 256, 0, stream>>>(Wq, Wk, Wv, wt);
    attn_kernel<<<1024, 256, 0, stream>>>(x, wt, (float*)d_out);
}

// Round 2
// 304.626 us; speedup vs baseline: 1.0354x; 1.0217x over previous
//
#include <hip/hip_runtime.h>

// Head_13: fused single-head causal attention, B=1024 T=128 C=384 HS=64, fp32 I/O.
// One block (4 waves) per batch. bf16 MFMA 32x32x16.
// Phase 1 (QKV proj): x staged to LDS via coalesced global_load_lds (16B, XOR-swizzled
// source, linear LDS dest). DEPTH-2 pipeline: 3x16KB LDS buffers, stages for chunks
// c+1,c+2 in flight across raw s_barrier with counted s_waitcnt vmcnt(N) (never 0 in
// the loop); W fragments prefetched 1 chunk ahead into a register double-buffer.
// Phase 2: LDS q/k/v, causal flash in-block, rowsum via shfl_xor butterfly.

typedef __attribute__((ext_vector_type(8)))  short  short8;   // 8 bf16 = 4 VGPR
typedef __attribute__((ext_vector_type(16))) float  floatx16; // MFMA 32x32 acc
typedef __attribute__((ext_vector_type(4)))  float  float4v;

#define T_DIM   128
#define C_DIM   384
#define HS      64
#define NCHUNK  12            // 384/32
#define SLAB    1536          // shorts per (c,ks,half) slab = 192 n * 8 k

#define QK_PITCH 68           // 64+4 bf16 -> 136 B row (8B-aligned, 2-way banks = free)
#define V_PITCH  132          // 128+4 bf16 -> 264 B
#define P_PITCH  132
#define Q_OFF 0
#define K_OFF 17408           // 128*136
#define V_OFF 34816
#define LDS_BYTES 51712       // V_OFF + 64*264
#define P_OFF 0               // P [128][132]*2 = 33792 overlays q + head of k (dead in 2b)
#define XS_OFF 0              // x staging: 3 x 16384 B overlays q/k/v (dead until epilogue)
#define XS_BUF 16384          // one chunk: 128 rows x 128 B (32 fp32), XOR-swizzled

#define MFMA(a,b,c) __builtin_amdgcn_mfma_f32_32x32x16_bf16((a),(b),(c),0,0,0)

__device__ inline unsigned short f2bf(float f){ // fp32 -> bf16 RTNE
    unsigned u = __builtin_bit_cast(unsigned, f);
    u += 0x7FFFu + ((u >> 16) & 1u);
    return (unsigned short)(u >> 16);
}

__device__ inline short8 ld_b64x2(const char* p){ // 16B fragment via two 8B LDS reads
    union { unsigned long long u[2]; short8 s; } r;
    r.u[0] = *(const unsigned long long*)(p);
    r.u[1] = *(const unsigned long long*)(p + 8);
    return r.s;
}

// W[q|k|v] fp32 [384][64] -> wt bf16 fragment-major: [c][ks][half][n=192][j=8]
// short index = ((c*2+ks)*2+half)*1536 + n*8 + j ; k_global = c*32+ks*16+half*8+j
__global__ void prep_wt(const float* __restrict__ Wq, const float* __restrict__ Wk,
                        const float* __restrict__ Wv, unsigned short* __restrict__ wt){
    int idx = blockIdx.x * 256 + threadIdx.x;
    if (idx >= 48 * SLAB) return;
    int slab = idx / SLAB;
    int rem  = idx - slab * SLAB;
    int n = rem >> 3, j = rem & 7;
    int half = slab & 1, ks = (slab >> 1) & 1, c = slab >> 2;
    int kg = c*32 + ks*16 + half*8 + j;
    const float* W = (n < 64) ? Wq : (n < 128) ? Wk : Wv;
    wt[idx] = f2bf(W[kg * HS + (n & 63)]);
}

__launch_bounds__(256, 2)
__global__ void attn_kernel(const float* __restrict__ x,
                            const unsigned short* __restrict__ wtg,
                            float* __restrict__ out){
    __shared__ __align__(16) char smem[LDS_BYTES];
    const int tid  = threadIdx.x;
    const int lane = tid & 63;
    const int wave = tid >> 6;
    const int l31  = lane & 31;
    const int half = lane >> 5;
    const int koff = half * 8;            // MFMA k-split: lanes 32-63 hold k+8..k+15
    const int b    = blockIdx.x;
    const float* xb = x + (size_t)b * (T_DIM * C_DIM);

    // ---------------- phase 1: [q|k|v] = x[b] @ Wt ------------------------------
    // x chunk (128 rows x 32 fp32) staged to LDS, coalesced, triple-buffered.
    // LDS layout is LINEAR (global_load_lds writes base + lane*16); the XOR swizzle
    // lives in the per-lane GLOBAL source address: LDS[r][cb] = x[r][cb ^ ((r&7)<<4)].
    // Readers apply the same XOR -> ds_read_b128 fragment gather is 4-way (not 32-way).
    const int mpair = wave & 1;           // rows 64*mpair .. +63 (2 M-blocks)
    const int ntri  = wave >> 1;          // wt cols 96*ntri .. +95 (3 N-blocks)
    const short8* wf = (const short8*)wtg;
    const int nbase = 96 * ntri + l31;

    // per-lane staging source: row group (lane>>3), 16B block (lane&7)^(lane>>3)
    const char* xsrc = (const char*)xb
                     + (lane >> 3) * (C_DIM * 4)
                     + ((((lane & 7) ^ (lane >> 3))) << 4);

    auto stage = [&](int c, int sb){      // 4 global_load_lds x 16B per thread
        #pragma unroll
        for (int i = 0; i < 4; ++i){
            const char* g = xsrc + (i*4 + wave) * (8 * C_DIM * 4) + c * 128;
            char*       l = smem + XS_OFF + sb * XS_BUF + (i*4 + wave) * 1024;
            __builtin_amdgcn_global_load_lds(
                (const __attribute__((address_space(1))) unsigned*)g,
                (__attribute__((address_space(3))) unsigned*)l,
                16, 0, 0);
        }
    };

    floatx16 acc[6] = {};                 // [nbl*2 + mbl]
    short8 bfr[2][2][3];                  // W fragments, double-buffered [c&1][ks][nbl]

    // prologue: bfr(0) issued first (oldest), then stage(0), stage(1).
    #pragma unroll
    for (int ks = 0; ks < 2; ++ks)
        #pragma unroll
        for (int nbl = 0; nbl < 3; ++nbl)
            bfr[0][ks][nbl] = wf[((0*2 + ks)*2 + half)*192 + nbase + 32*nbl];
    stage(0, 0);
    stage(1, 1);
    // stage(0) done <=> vmcnt <= 4 (only stage(1) may remain; bfr(0) also drained)
    asm volatile("s_waitcnt vmcnt(4)" ::: "memory");
    __builtin_amdgcn_s_barrier();
    asm volatile("" ::: "memory");

    #pragma unroll
    for (int c = 0; c < NCHUNK; ++c){
        // in flight on entry: stage(c+1) [4], (c>=1: bfr(c) retired by compiler waits)
        // issue next W prefetch (older than next stage for clean vmcnt accounting)
        if (c + 1 < NCHUNK){
            #pragma unroll
            for (int ks = 0; ks < 2; ++ks)
                #pragma unroll
                for (int nbl = 0; nbl < 3; ++nbl)
                    bfr[(c+1)&1][ks][nbl] =
                        wf[(((c+1)*2 + ks)*2 + half)*192 + nbase + 32*nbl];
        }
        if (c + 2 < NCHUNK) stage(c + 2, (c + 2) % 3);   // depth-2 prefetch

        // A fragments: swizzled LDS read of buf[c%3] + fp32->bf16 convert
        const char* sbuf = smem + XS_OFF + (c % 3) * XS_BUF;
        short8 afr[2][2];
        #pragma unroll
        for (int mbl = 0; mbl < 2; ++mbl){
            const int R  = 64*mpair + 32*mbl + l31;
            const char* rp = sbuf + R * 128;
            const int sw = (R & 7) << 4;
            #pragma unroll
            for (int ks = 0; ks < 2; ++ks){
                const int cb = ks*64 + half*32;        // byte col of 8-fp32 fragment
                float4v lo = *(const float4v*)(rp + ((cb     ) ^ sw));
                float4v hi = *(const float4v*)(rp + ((cb + 16) ^ sw));
                short8 a;
                a[0]=(short)f2bf(lo[0]); a[1]=(short)f2bf(lo[1]);
                a[2]=(short)f2bf(lo[2]); a[3]=(short)f2bf(lo[3]);
                a[4]=(short)f2bf(hi[0]); a[5]=(short)f2bf(hi[1]);
                a[6]=(short)f2bf(hi[2]); a[7]=(short)f2bf(hi[3]);
                afr[ks][mbl] = a;
            }
        }
        #pragma unroll
        for (int ks = 0; ks < 2; ++ks)
            #pragma unroll
            for (int nbl = 0; nbl < 3; ++nbl){
                acc[nbl*2+0] = MFMA(afr[ks][0], bfr[c&1][ks][nbl], acc[nbl*2+0]);
                acc[nbl*2+1] = MFMA(afr[ks][1], bfr[c&1][ks][nbl], acc[nbl*2+1]);
            }

        // pre-barrier counted wait: retire this wave's stage(c+1), keep the rest
        // in flight. Young ops after stage(c+1): c<=9: bfr(c+1)[6]+stage(c+2)[4]=10;
        // c==10: bfr(11)[6]=6; c==11: no further buffer reads -> no barrier.
        if (c + 1 < NCHUNK){
            if (c < NCHUNK - 2) asm volatile("s_waitcnt vmcnt(10)" ::: "memory");
            else                asm volatile("s_waitcnt vmcnt(6)"  ::: "memory");
            __builtin_amdgcn_s_barrier();
            asm volatile("" ::: "memory");
        }
    }
    __syncthreads();   // full drain: all staging reads done before epilogue overwrites

    // write q,k (row-major, softmax scale*log2e folded into q) and v (h-major) to LDS
    const float QSCALE = 0.125f * 1.44269504088896f;
    #pragma unroll
    for (int nbl = 0; nbl < 3; ++nbl)
        #pragma unroll
        for (int mbl = 0; mbl < 2; ++mbl){
            floatx16 A = acc[nbl*2+mbl];
            int nb = 3*ntri + nbl;        // 0..5: q q k k v v
            int mb = 2*mpair + mbl;
            if (nb < 4){
                int base  = (nb < 2) ? Q_OFF : K_OFF;
                int col   = 32 * (nb & 1) + l31;
                float sc  = (nb < 2) ? QSCALE : 1.0f;
                char* bp  = smem + base + col * 2;
                #pragma unroll
                for (int r = 0; r < 16; ++r){
                    int t = 32*mb + (r&3) + 8*(r>>2) + 4*half;   // verified C/D row map
                    *(unsigned short*)(bp + t * (QK_PITCH*2)) = f2bf(A[r] * sc);
                }
            } else {
                int h = 32*(nb-4) + l31;
                char* bp = smem + V_OFF + h * (V_PITCH*2);
                #pragma unroll
                for (int g = 0; g < 4; ++g){
                    int t0 = 32*mb + 8*g + 4*half;   // regs 4g..4g+3 = 4 consecutive rows
                    union { unsigned short s[4]; unsigned long long u; } pk;
                    pk.s[0]=f2bf(A[4*g+0]); pk.s[1]=f2bf(A[4*g+1]);
                    pk.s[2]=f2bf(A[4*g+2]); pk.s[3]=f2bf(A[4*g+3]);
                    *(unsigned long long*)(bp + t0*2) = pk.u;
                }
            }
        }
    __syncthreads();

    // ---------------- phase 2a: S = q k^T (causal), P = exp2(S) ----------------
    // wave w owns rows [32w, 32w+32); tiles st > w fully masked -> skipped.
    floatx16 accS[4] = {};
    #pragma unroll
    for (int ks = 0; ks < 4; ++ks){
        short8 aq = ld_b64x2(smem + Q_OFF + (32*wave + l31)*(QK_PITCH*2) + (ks*16 + koff)*2);
        #pragma unroll
        for (int st = 0; st < 4; ++st)
            if (st <= wave){
                short8 bk = ld_b64x2(smem + K_OFF + (32*st + l31)*(QK_PITCH*2) + (ks*16 + koff)*2);
                accS[st] = MFMA(aq, bk, accS[st]);
            }
    }
    // |logit| <~ 8 -> exp2 safe in fp32 without max-subtraction
    #pragma unroll
    for (int st = 0; st < 4; ++st)
        if (st <= wave){
            #pragma unroll
            for (int r = 0; r < 16; ++r){
                int trow = (r&3) + 8*(r>>2) + 4*half;
                float e = exp2f(accS[st][r]);
                if (st == wave && l31 > trow) e = 0.0f;   // causal mask, diagonal tile
                accS[st][r] = e;
            }
        }

    // rowsum -> 1/l per (reg, half) via butterfly within each 32-lane half.
    // accS[st] for st > wave is still all-zero, so sum all 4 unconditionally.
    float linv[16];
    #pragma unroll
    for (int r = 0; r < 16; ++r){
        float l = accS[0][r] + accS[1][r] + accS[2][r] + accS[3][r];
        #pragma unroll
        for (int m = 1; m <= 16; m <<= 1)
            l += __shfl_xor(l, m);
        linv[r] = 1.0f / l;
    }
    __syncthreads();     // all waves done reading q,k (P overlays them)

    // ---------------- phase 2b: P -> LDS (A-layout), O = P v -------------------
    #pragma unroll
    for (int st = 0; st < 4; ++st)
        if (st <= wave){
            char* bp = smem + P_OFF + (32*st + l31) * 2;
            #pragma unroll
            for (int r = 0; r < 16; ++r){
                int t = 32*wave + (r&3) + 8*(r>>2) + 4*half;
                *(unsigned short*)(bp + t * (P_PITCH*2)) = f2bf(accS[st][r]);
            }
        }
    __syncthreads();

    floatx16 accO0 = {}, accO1 = {};
    const int nks = 2 * (wave + 1);       // P == 0 / unwritten beyond diagonal block
    #pragma unroll
    for (int ks = 0; ks < 8; ++ks)
        if (ks < nks){
            short8 ap  = ld_b64x2(smem + P_OFF + (32*wave + l31)*(P_PITCH*2) + (ks*16 + koff)*2);
            short8 bv0 = ld_b64x2(smem + V_OFF + l31        *(V_PITCH*2) + (ks*16 + koff)*2);
            short8 bv1 = ld_b64x2(smem + V_OFF + (l31 + 32) *(V_PITCH*2) + (ks*16 + koff)*2);
            accO0 = MFMA(ap, bv0, accO0);
            accO1 = MFMA(ap, bv1, accO1);
        }

    // normalize with register-resident 1/l and store fp32 (coalesced over l31)
    float* ob = out + (size_t)b * (T_DIM * HS);
    #pragma unroll
    for (int r = 0; r < 16; ++r){
        int t = 32*wave + (r&3) + 8*(r>>2) + 4*half;
        ob[t*HS + l31]      = accO0[r] * linv[r];
        ob[t*HS + l31 + 32] = accO1[r] * linv[r];
    }
}

extern "C" void kernel_launch(void* const* d_in, const int* in_sizes, int n_in,
                              void* d_out, int out_size, void* d_ws, size_t ws_size,
                              hipStream_t stream){
    const float* x  = (const float*)d_in[0];
    const float* Wq = (const float*)d_in[1];
    const float* Wk = (const float*)d_in[2];
    const float* Wv = (const float*)d_in[3];
    unsigned short* wt = (unsigned short*)d_ws;   // 48*1536*2 = 147456 B used

    prep_wt<<<288, 256, 0, stream>>>(Wq, Wk, Wv, wt);
    attn_kernel<<<1024, 256, 0, stream>>>(x, wt, (float*)d_out);
}

// Round 3
// 304.360 us; speedup vs baseline: 1.0363x; 1.0009x over previous
//
#include <hip/hip_runtime.h>

// Head_13: fused single-head causal attention, B=1024 T=128 C=384 HS=64, fp32 I/O.
// One block (4 waves) per batch. bf16 MFMA 32x32x16.
// Phase 1 (QKV proj): REG-STAGED depth-2 pipeline. Each thread loads a 64B strip of
// chunk c+2 to VGPRs (coalesced dwordx4 x4, compiler-counted vmcnt - no LDS-DMA alias
// hazard), converts fp32->bf16 ONCE, ds_writes a bf16 chunk buffer (pitch 80B).
// Per-chunk barrier drains lgkmcnt only; vmcnt never drained in-loop.
// W pre-packed fragment-major bf16 (L2-resident), register double-buffered.
// Phase 2: LDS q/k/v, causal flash in-block, rowsum via shfl_xor butterfly.

typedef __attribute__((ext_vector_type(8)))  short  short8;   // 8 bf16 = 4 VGPR
typedef __attribute__((ext_vector_type(16))) float  floatx16; // MFMA 32x32 acc
typedef __attribute__((ext_vector_type(4)))  float  float4v;

#define T_DIM   128
#define C_DIM   384
#define HS      64
#define NCHUNK  12            // 384/32
#define SLAB    1536          // shorts per (c,ks,half) slab = 192 n * 8 k

#define QK_PITCH 68           // 64+4 bf16 -> 136 B row (8B-aligned, 2-way banks = free)
#define V_PITCH  132          // 128+4 bf16 -> 264 B
#define P_PITCH  132
#define Q_OFF 0
#define K_OFF 17408           // 128*136
#define V_OFF 34816
#define LDS_BYTES 51712       // V_OFF + 64*264
#define P_OFF 0               // P [128][132]*2 = 33792 overlays q + head of k (dead in 2b)
#define XS_OFF 0              // x bf16 staging: 2 x 10240 B overlays q (dead until epilogue)
#define XS_BUF 10240          // one chunk: 128 rows x 80 B pitch (64 B bf16 + 16 pad)
#define XP    80              // chunk-buffer row pitch in bytes (16-aligned; 8-row bank period)

#define MFMA(a,b,c) __builtin_amdgcn_mfma_f32_32x32x16_bf16((a),(b),(c),0,0,0)

__device__ inline unsigned short f2bf(float f){ // fp32 -> bf16 RTNE
    unsigned u = __builtin_bit_cast(unsigned, f);
    u += 0x7FFFu + ((u >> 16) & 1u);
    return (unsigned short)(u >> 16);
}

__device__ inline short8 ld_b64x2(const char* p){ // 16B fragment via two 8B LDS reads
    union { unsigned long long u[2]; short8 s; } r;
    r.u[0] = *(const unsigned long long*)(p);
    r.u[1] = *(const unsigned long long*)(p + 8);
    return r.s;
}

// W[q|k|v] fp32 [384][64] -> wt bf16 fragment-major: [c][ks][half][n=192][j=8]
// short index = ((c*2+ks)*2+half)*1536 + n*8 + j ; k_global = c*32+ks*16+half*8+j
__global__ void prep_wt(const float* __restrict__ Wq, const float* __restrict__ Wk,
                        const float* __restrict__ Wv, unsigned short* __restrict__ wt){
    int idx = blockIdx.x * 256 + threadIdx.x;
    if (idx >= 48 * SLAB) return;
    int slab = idx / SLAB;
    int rem  = idx - slab * SLAB;
    int n = rem >> 3, j = rem & 7;
    int half = slab & 1, ks = (slab >> 1) & 1, c = slab >> 2;
    int kg = c*32 + ks*16 + half*8 + j;
    const float* W = (n < 64) ? Wq : (n < 128) ? Wk : Wv;
    wt[idx] = f2bf(W[kg * HS + (n & 63)]);
}

__launch_bounds__(256, 2)
__global__ void attn_kernel(const float* __restrict__ x,
                            const unsigned short* __restrict__ wtg,
                            float* __restrict__ out){
    __shared__ __align__(16) char smem[LDS_BYTES];
    const int tid  = threadIdx.x;
    const int lane = tid & 63;
    const int wave = tid >> 6;
    const int l31  = lane & 31;
    const int half = lane >> 5;
    const int koff = half * 8;            // MFMA k-split: lanes 32-63 hold k+8..k+15
    const int b    = blockIdx.x;
    const float* xb = x + (size_t)b * (T_DIM * C_DIM);

    // ---------------- phase 1: [q|k|v] = x[b] @ Wt ------------------------------
    const int mpair = wave & 1;           // rows 64*mpair .. +63 (2 M-blocks)
    const int ntri  = wave >> 1;          // wt cols 96*ntri .. +95 (3 N-blocks)
    const short8* wf = (const short8*)wtg;
    const int nbase = 96 * ntri + l31;

    // staging role: thread -> (row, 16-float half-strip) of the 128x32 fp32 chunk
    const int srow  = tid >> 1;           // 0..127
    const int shalf = tid & 1;            // floats [16*shalf, 16*shalf+16)
    char* const bw0 = smem + XS_OFF + srow * XP + shalf * 32;   // bf16 dest (32 B)

    float4v ldreg[2][4];                  // fp32 in-flight strips, 2 chunks deep
    auto xload = [&](int c, int s){       // 4 coalesced dwordx4, compiler-counted vmcnt
        const float4v* g = (const float4v*)(xb + srow * C_DIM + c * 32 + shalf * 16);
        ldreg[s][0] = g[0]; ldreg[s][1] = g[1];
        ldreg[s][2] = g[2]; ldreg[s][3] = g[3];
    };
    auto cw = [&](int s, int sb){         // convert once -> bf16 chunk buffer
        short8 o0, o1;
        #pragma unroll
        for (int j = 0; j < 8; ++j){
            o0[j] = (short)f2bf(ldreg[s][j >> 2    ][j & 3]);
            o1[j] = (short)f2bf(ldreg[s][(j >> 2)+2][j & 3]);
        }
        char* p = bw0 + sb * XS_BUF;
        *(short8*)(p)      = o0;
        *(short8*)(p + 16) = o1;
    };

    floatx16 acc[6] = {};                 // [nbl*2 + mbl]
    short8 bfr[2][2][3];                  // W fragments, double-buffered [c&1][ks][nbl]

    // prologue: chunks 0,1 to regs; W(0); chunk 0 -> LDS
    xload(0, 0);
    xload(1, 1);
    #pragma unroll
    for (int ks = 0; ks < 2; ++ks)
        #pragma unroll
        for (int nbl = 0; nbl < 3; ++nbl)
            bfr[0][ks][nbl] = wf[((0*2 + ks)*2 + half)*192 + nbase + 32*nbl];
    cw(0, 0);                             // compiler waits only on ldreg[0]'s loads
    asm volatile("s_waitcnt lgkmcnt(0)" ::: "memory");
    __builtin_amdgcn_s_barrier();
    asm volatile("" ::: "memory");

    #pragma unroll
    for (int c = 0; c < NCHUNK; ++c){
        // issue next-next chunk loads into the slot freed last iteration
        if (c + 2 < NCHUNK) xload(c + 2, c & 1);
        // W prefetch for next chunk (L2-resident)
        if (c + 1 < NCHUNK){
            #pragma unroll
            for (int ks = 0; ks < 2; ++ks)
                #pragma unroll
                for (int nbl = 0; nbl < 3; ++nbl)
                    bfr[(c+1)&1][ks][nbl] =
                        wf[(((c+1)*2 + ks)*2 + half)*192 + nbase + 32*nbl];
        }

        // A fragments: direct bf16 ds_read_b128 from buf[c&1] (lgkm only, no vmcnt)
        const char* sbuf = smem + XS_OFF + (c & 1) * XS_BUF;
        short8 afr[2][2];
        #pragma unroll
        for (int mbl = 0; mbl < 2; ++mbl){
            const int R = 64*mpair + 32*mbl + l31;
            #pragma unroll
            for (int ks = 0; ks < 2; ++ks)
                afr[ks][mbl] = *(const short8*)(sbuf + R * XP + ks*32 + half*16);
        }
        #pragma unroll
        for (int ks = 0; ks < 2; ++ks)
            #pragma unroll
            for (int nbl = 0; nbl < 3; ++nbl){
                acc[nbl*2+0] = MFMA(afr[ks][0], bfr[c&1][ks][nbl], acc[nbl*2+0]);
                acc[nbl*2+1] = MFMA(afr[ks][1], bfr[c&1][ks][nbl], acc[nbl*2+1]);
            }

        // convert+write chunk c+1 into the other buffer; barrier drains LDS only.
        if (c + 1 < NCHUNK){
            cw((c+1)&1, (c+1)&1);         // waits (precisely) on ldreg[(c+1)&1] loads
            asm volatile("s_waitcnt lgkmcnt(0)" ::: "memory");
            __builtin_amdgcn_s_barrier();
            asm volatile("" ::: "memory");
        }
    }
    __syncthreads();   // full drain: all chunk-buffer reads done before epilogue overwrites

    // write q,k (row-major, softmax scale*log2e folded into q) and v (h-major) to LDS
    const float QSCALE = 0.125f * 1.44269504088896f;
    #pragma unroll
    for (int nbl = 0; nbl < 3; ++nbl)
        #pragma unroll
        for (int mbl = 0; mbl < 2; ++mbl){
            floatx16 A = acc[nbl*2+mbl];
            int nb = 3*ntri + nbl;        // 0..5: q q k k v v
            int mb = 2*mpair + mbl;
            if (nb < 4){
                int base  = (nb < 2) ? Q_OFF : K_OFF;
                int col   = 32 * (nb & 1) + l31;
                float sc  = (nb < 2) ? QSCALE : 1.0f;
                char* bp  = smem + base + col * 2;
                #pragma unroll
                for (int r = 0; r < 16; ++r){
                    int t = 32*mb + (r&3) + 8*(r>>2) + 4*half;   // verified C/D row map
                    *(unsigned short*)(bp + t * (QK_PITCH*2)) = f2bf(A[r] * sc);
                }
            } else {
                int h = 32*(nb-4) + l31;
                char* bp = smem + V_OFF + h * (V_PITCH*2);
                #pragma unroll
                for (int g = 0; g < 4; ++g){
                    int t0 = 32*mb + 8*g + 4*half;   // regs 4g..4g+3 = 4 consecutive rows
                    union { unsigned short s[4]; unsigned long long u; } pk;
                    pk.s[0]=f2bf(A[4*g+0]); pk.s[1]=f2bf(A[4*g+1]);
                    pk.s[2]=f2bf(A[4*g+2]); pk.s[3]=f2bf(A[4*g+3]);
                    *(unsigned long long*)(bp + t0*2) = pk.u;
                }
            }
        }
    __syncthreads();

    // ---------------- phase 2a: S = q k^T (causal), P = exp2(S) ----------------
    // wave w owns rows [32w, 32w+32); tiles st > w fully masked -> skipped.
    floatx16 accS[4] = {};
    #pragma unroll
    for (int ks = 0; ks < 4; ++ks){
        short8 aq = ld_b64x2(smem + Q_OFF + (32*wave + l31)*(QK_PITCH*2) + (ks*16 + koff)*2);
        #pragma unroll
        for (int st = 0; st < 4; ++st)
            if (st <= wave){
                short8 bk = ld_b64x2(smem + K_OFF + (32*st + l31)*(QK_PITCH*2) + (ks*16 + koff)*2);
                accS[st] = MFMA(aq, bk, accS[st]);
            }
    }
    // |logit| <~ 8 -> exp2 safe in fp32 without max-subtraction
    #pragma unroll
    for (int st = 0; st < 4; ++st)
        if (st <= wave){
            #pragma unroll
            for (int r = 0; r < 16; ++r){
                int trow = (r&3) + 8*(r>>2) + 4*half;
                float e = exp2f(accS[st][r]);
                if (st == wave && l31 > trow) e = 0.0f;   // causal mask, diagonal tile
                accS[st][r] = e;
            }
        }

    // rowsum -> 1/l per (reg, half) via butterfly within each 32-lane half.
    // accS[st] for st > wave is still all-zero, so sum all 4 unconditionally.
    float linv[16];
    #pragma unroll
    for (int r = 0; r < 16; ++r){
        float l = accS[0][r] + accS[1][r] + accS[2][r] + accS[3][r];
        #pragma unroll
        for (int m = 1; m <= 16; m <<= 1)
            l += __shfl_xor(l, m);
        linv[r] = 1.0f / l;
    }
    __syncthreads();     // all waves done reading q,k (P overlays them)

    // ---------------- phase 2b: P -> LDS (A-layout), O = P v -------------------
    #pragma unroll
    for (int st = 0; st < 4; ++st)
        if (st <= wave){
            char* bp = smem + P_OFF + (32*st + l31) * 2;
            #pragma unroll
            for (int r = 0; r < 16; ++r){
                int t = 32*wave + (r&3) + 8*(r>>2) + 4*half;
                *(unsigned short*)(bp + t * (P_PITCH*2)) = f2bf(accS[st][r]);
            }
        }
    __syncthreads();

    floatx16 accO0 = {}, accO1 = {};
    const int nks = 2 * (wave + 1);       // P == 0 / unwritten beyond diagonal block
    #pragma unroll
    for (int ks = 0; ks < 8; ++ks)
        if (ks < nks){
            short8 ap  = ld_b64x2(smem + P_OFF + (32*wave + l31)*(P_PITCH*2) + (ks*16 + koff)*2);
            short8 bv0 = ld_b64x2(smem + V_OFF + l31        *(V_PITCH*2) + (ks*16 + koff)*2);
            short8 bv1 = ld_b64x2(smem + V_OFF + (l31 + 32) *(V_PITCH*2) + (ks*16 + koff)*2);
            accO0 = MFMA(ap, bv0, accO0);
            accO1 = MFMA(ap, bv1, accO1);
        }

    // normalize with register-resident 1/l and store fp32 (coalesced over l31)
    float* ob = out + (size_t)b * (T_DIM * HS);
    #pragma unroll
    for (int r = 0; r < 16; ++r){
        int t = 32*wave + (r&3) + 8*(r>>2) + 4*half;
        ob[t*HS + l31]      = accO0[r] * linv[r];
        ob[t*HS + l31 + 32] = accO1[r] * linv[r];
    }
}

extern "C" void kernel_launch(void* const* d_in, const int* in_sizes, int n_in,
                              void* d_out, int out_size, void* d_ws, size_t ws_size,
                              hipStream_t stream){
    const float* x  = (const float*)d_in[0];
    const float* Wq = (const float*)d_in[1];
    const float* Wk = (const float*)d_in[2];
    const float* Wv = (const float*)d_in[3];
    unsigned short* wt = (unsigned short*)d_ws;   // 48*1536*2 = 147456 B used

    prep_wt<<<288, 256, 0, stream>>>(Wq, Wk, Wv, wt);
    attn_kernel<<<1024, 256, 0, stream>>>(x, wt, (float*)d_out);
}